// Round 9
// baseline (28.321 us; speedup 1.0000x reference)
//
#include <hip/hip_runtime.h>

// out[b,f] = x[b,f] * S. Algebraic collapse of the reference:
//   Re(factor_c) = gain_c * cos(phase_c + 0.5*D*(wl_c - mean(wl))^2) * sigmoid(aw_c)
//   S = sum_k softmax(aw)[k] * sum_c Re(factor_c) * M[c,k]
//
// Accuracy: phases ~1e5 break native-cosf f32 range reduction (R2 fail
// 2.7e-2). Reduce mod 2*pi in double ARITHMETIC only (no f64
// transcendentals), then cosf on the small argument -> absmax 2e-3.
//
// Perf history (timed): unroll-2 cached = 26.90us (best); R7 simple
// cached = 27.08; R1 + nt scalar stores = 27.4; vector nt = 28.5;
// 8-batch+nt = 31.1; no-loop = 33.8. nt stores lose LLC write-back;
// deep batch was confounded with nt. This round: unroll-4, cached both
// ways — 4 independent loads in flight, 24 MB footprint spread, no nt.

typedef float f32x4 __attribute__((ext_vector_type(4)));

__global__ __launch_bounds__(256) void wdm_scale_kernel(
    const float* __restrict__ x,
    const float* __restrict__ gains,
    const float* __restrict__ phases,
    const float* __restrict__ aw,
    const float* __restrict__ disp,
    const float* __restrict__ ct,     // [3][3] row-major, M[c][k]
    const float* __restrict__ wl,
    float* __restrict__ out,
    int n4)                            // number of float4 elements
{
    // ---- scalar S, all-thread redundant, f64 only for phase reduction ----
    const double TWO_PI     = 6.283185307179586;
    const double INV_TWO_PI = 0.15915494309189535;

    const float w0 = wl[0], w1 = wl[1], w2 = wl[2];
    const float wlm = (w0 + w1 + w2) * (1.0f / 3.0f);
    const double D = (double)disp[0];

    const float a0 = aw[0], a1 = aw[1], a2 = aw[2];
    const float awm = fmaxf(fmaxf(a0, a1), a2);
    const float wls[3] = {w0, w1, w2};
    const float as[3]  = {a0, a1, a2};

    float re[3], ex[3];
    float sumex = 0.0f;
    #pragma unroll
    for (int c = 0; c < 3; ++c) {
        double d  = (double)wls[c] - (double)wlm;
        double ph = (double)phases[c] + 0.5 * D * d * d;
        double k = __builtin_rint(ph * INV_TWO_PI);
        float r  = (float)(ph - k * TWO_PI);
        float sg = 1.0f / (1.0f + expf(-as[c]));
        re[c] = gains[c] * cosf(r) * sg;
        ex[c] = expf(as[c] - awm);
        sumex += ex[c];
    }
    float S = 0.0f;
    #pragma unroll
    for (int k = 0; k < 3; ++k) {
        float acc = 0.0f;
        #pragma unroll
        for (int c = 0; c < 3; ++c) acc += re[c] * ct[c * 3 + k];
        S += (ex[k] / sumex) * acc;
    }

    // ---- streaming scale: unroll-4 grid-stride, cached both ways ----
    const f32x4* __restrict__ x4 = (const f32x4*)x;
    f32x4* __restrict__ o4 = (f32x4*)out;

    const int stride = gridDim.x * blockDim.x;
    int i = blockIdx.x * blockDim.x + threadIdx.x;
    for (; i + 3 * stride < n4; i += 4 * stride) {
        f32x4 v0 = x4[i];
        f32x4 v1 = x4[i + stride];
        f32x4 v2 = x4[i + 2 * stride];
        f32x4 v3 = x4[i + 3 * stride];
        v0 *= S;
        v1 *= S;
        v2 *= S;
        v3 *= S;
        o4[i] = v0;
        o4[i + stride] = v1;
        o4[i + 2 * stride] = v2;
        o4[i + 3 * stride] = v3;
    }
    for (; i < n4; i += stride) {
        f32x4 v = x4[i];
        v *= S;
        o4[i] = v;
    }
}

extern "C" void kernel_launch(void* const* d_in, const int* in_sizes, int n_in,
                              void* d_out, int out_size, void* d_ws, size_t ws_size,
                              hipStream_t stream) {
    const float* x      = (const float*)d_in[0];
    const float* gains  = (const float*)d_in[1];
    const float* phases = (const float*)d_in[2];
    const float* aw     = (const float*)d_in[3];
    const float* disp   = (const float*)d_in[4];
    const float* ct     = (const float*)d_in[5];
    const float* wl     = (const float*)d_in[6];
    float* out = (float*)d_out;

    int n = in_sizes[0];                // 4096*4096, divisible by 4
    int n4 = n >> 2;

    int block = 256;
    long want = ((long)n4 + block - 1) / block;
    int grid = (int)(want < 2048 ? want : 2048);

    wdm_scale_kernel<<<grid, block, 0, stream>>>(x, gains, phases, aw, disp,
                                                 ct, wl, out, n4);
}

// Round 10
// 27.341 us; speedup vs baseline: 1.0358x; 1.0358x over previous
//
#include <hip/hip_runtime.h>

// out[b,f] = x[b,f] * S. Algebraic collapse of the reference:
//   Re(factor_c) = gain_c * cos(phase_c + 0.5*D*(wl_c - mean(wl))^2) * sigmoid(aw_c)
//   S = sum_k softmax(aw)[k] * sum_c Re(factor_c) * M[c,k]
//
// Accuracy: phases ~1e5 break native-cosf f32 range reduction (R2 fail
// 2.7e-2). Reduce mod 2*pi in double ARITHMETIC only (no f64
// transcendentals), then cosf on the small argument -> absmax 2e-3.
//
// Perf history (timed): unroll-2 cached = 26.90us (BEST); unroll-1 =
// 27.08; unroll-4 = 28.32; 8-batch+nt = 31.1; nt stores = 28.5;
// no-loop = 33.8. MLP axis concave with optimum at 2. nt stores lose
// LLC write-back (128 MB working set fits 256 MB Infinity Cache).
// This is the locked-in best configuration: 2048 blocks x 256 threads,
// unroll-2 grid-stride, cached load/store, redundant f32 prologue.

typedef float f32x4 __attribute__((ext_vector_type(4)));

__global__ __launch_bounds__(256) void wdm_scale_kernel(
    const float* __restrict__ x,
    const float* __restrict__ gains,
    const float* __restrict__ phases,
    const float* __restrict__ aw,
    const float* __restrict__ disp,
    const float* __restrict__ ct,     // [3][3] row-major, M[c][k]
    const float* __restrict__ wl,
    float* __restrict__ out,
    int n4)                            // number of float4 elements
{
    // ---- scalar S, all-thread redundant, f64 only for phase reduction ----
    const double TWO_PI     = 6.283185307179586;
    const double INV_TWO_PI = 0.15915494309189535;

    const float w0 = wl[0], w1 = wl[1], w2 = wl[2];
    const float wlm = (w0 + w1 + w2) * (1.0f / 3.0f);
    const double D = (double)disp[0];

    const float a0 = aw[0], a1 = aw[1], a2 = aw[2];
    const float awm = fmaxf(fmaxf(a0, a1), a2);
    const float wls[3] = {w0, w1, w2};
    const float as[3]  = {a0, a1, a2};

    float re[3], ex[3];
    float sumex = 0.0f;
    #pragma unroll
    for (int c = 0; c < 3; ++c) {
        double d  = (double)wls[c] - (double)wlm;
        double ph = (double)phases[c] + 0.5 * D * d * d;
        double k = __builtin_rint(ph * INV_TWO_PI);
        float r  = (float)(ph - k * TWO_PI);
        float sg = 1.0f / (1.0f + expf(-as[c]));
        re[c] = gains[c] * cosf(r) * sg;
        ex[c] = expf(as[c] - awm);
        sumex += ex[c];
    }
    float S = 0.0f;
    #pragma unroll
    for (int k = 0; k < 3; ++k) {
        float acc = 0.0f;
        #pragma unroll
        for (int c = 0; c < 3; ++c) acc += re[c] * ct[c * 3 + k];
        S += (ex[k] / sumex) * acc;
    }

    // ---- streaming scale: unroll-2 grid-stride, cached both ways ----
    const f32x4* __restrict__ x4 = (const f32x4*)x;
    f32x4* __restrict__ o4 = (f32x4*)out;

    const int stride = gridDim.x * blockDim.x;
    int i = blockIdx.x * blockDim.x + threadIdx.x;
    for (; i + stride < n4; i += 2 * stride) {
        f32x4 v0 = x4[i];
        f32x4 v1 = x4[i + stride];
        v0 *= S;
        v1 *= S;
        o4[i] = v0;
        o4[i + stride] = v1;
    }
    for (; i < n4; i += stride) {
        f32x4 v = x4[i];
        v *= S;
        o4[i] = v;
    }
}

extern "C" void kernel_launch(void* const* d_in, const int* in_sizes, int n_in,
                              void* d_out, int out_size, void* d_ws, size_t ws_size,
                              hipStream_t stream) {
    const float* x      = (const float*)d_in[0];
    const float* gains  = (const float*)d_in[1];
    const float* phases = (const float*)d_in[2];
    const float* aw     = (const float*)d_in[3];
    const float* disp   = (const float*)d_in[4];
    const float* ct     = (const float*)d_in[5];
    const float* wl     = (const float*)d_in[6];
    float* out = (float*)d_out;

    int n = in_sizes[0];                // 4096*4096, divisible by 4
    int n4 = n >> 2;

    int block = 256;
    long want = ((long)n4 + block - 1) / block;
    int grid = (int)(want < 2048 ? want : 2048);

    wdm_scale_kernel<<<grid, block, 0, stream>>>(x, gains, phases, aw, disp,
                                                 ct, wl, out, n4);
}